// Round 1
// baseline (542.687 us; speedup 1.0000x reference)
//
#include <hip/hip_runtime.h>
#include <cmath>

#define TBL_SIZE (1u << 19)
#define TBL_MASK (TBL_SIZE - 1u)
#define PRIME1 2654435761u
#define PRIME2 805459861u
#define NUM_LEVELS 16

struct ScaleArgs { float s[NUM_LEVELS]; };

__global__ __launch_bounds__(256) void HashEncoding_88837103551034_kernel(
    const float* __restrict__ x,
    const float* __restrict__ table,
    float* __restrict__ out,
    int npoints,
    ScaleArgs sc)
{
    int gid = blockIdx.x * blockDim.x + threadIdx.x;
    int n = gid >> 3;          // point index
    int pair = gid & 7;        // which pair of levels (0..7)
    if (n >= npoints) return;

    // x in [-1,1] -> [0,1]; same f32 ops as the reference (mul, add)
    float x0 = x[(size_t)n * 3 + 0] * 0.5f + 0.5f;
    float x1 = x[(size_t)n * 3 + 1] * 0.5f + 0.5f;
    float x2 = x[(size_t)n * 3 + 2] * 0.5f + 0.5f;

    float acc[4];

    #pragma unroll
    for (int i = 0; i < 2; ++i) {
        int l = pair * 2 + i;
        float s = sc.s[l];
        float sx = x0 * s, sy = x1 * s, sz = x2 * s;
        float fx = floorf(sx), fy = floorf(sy), fz = floorf(sz);
        float ox = sx - fx, oy = sy - fy, oz = sz - fz;

        // uint32 products: low 19 bits identical to int64 reference (coords >= 0)
        uint32_t hx0 = (uint32_t)(int)fx;                    // * 1
        uint32_t hx1 = (uint32_t)(int)ceilf(sx);
        uint32_t hy0 = (uint32_t)(int)fy        * PRIME1;
        uint32_t hy1 = (uint32_t)(int)ceilf(sy) * PRIME1;
        uint32_t hz0 = (uint32_t)(int)fz        * PRIME2;
        uint32_t hz1 = (uint32_t)(int)ceilf(sz) * PRIME2;

        const float2* tb = reinterpret_cast<const float2*>(table) + (size_t)l * TBL_SIZE;

        float e0 = 0.f, e1 = 0.f;
        // corner bit b: (b>>2)&1 -> x uses ceil, (b>>1)&1 -> y, b&1 -> z
        #pragma unroll
        for (int b = 0; b < 8; ++b) {
            uint32_t h = ((b & 4) ? hx1 : hx0)
                       ^ ((b & 2) ? hy1 : hy0)
                       ^ ((b & 1) ? hz1 : hz0);
            float w = ((b & 4) ? ox : 1.f - ox)
                    * ((b & 2) ? oy : 1.f - oy)
                    * ((b & 1) ? oz : 1.f - oz);
            float2 f = tb[h & TBL_MASK];
            e0 += f.x * w;
            e1 += f.y * w;
        }
        acc[i * 2 + 0] = e0;
        acc[i * 2 + 1] = e1;
    }

    float4 res;
    res.x = acc[0]; res.y = acc[1]; res.z = acc[2]; res.w = acc[3];
    *reinterpret_cast<float4*>(out + (size_t)n * 32 + pair * 4) = res;
}

extern "C" void kernel_launch(void* const* d_in, const int* in_sizes, int n_in,
                              void* d_out, int out_size, void* d_ws, size_t ws_size,
                              hipStream_t stream) {
    const float* x = (const float*)d_in[0];
    const float* table = (const float*)d_in[1];
    float* out = (float*)d_out;
    int npoints = in_sizes[0] / 3;

    // Per-level resolutions, replicating numpy's double-precision op sequence:
    // growth = exp((log(1024)-log(16))/15); s[l] = floor(16 * growth**l)
    ScaleArgs sc;
    double growth = std::exp((std::log(1024.0) - std::log(16.0)) / 15.0);
    for (int l = 0; l < NUM_LEVELS; ++l) {
        sc.s[l] = (float)std::floor(16.0 * std::pow(growth, (double)l));
    }

    int nthreads = npoints * 8;
    int block = 256;
    int grid = (nthreads + block - 1) / block;
    HashEncoding_88837103551034_kernel<<<grid, block, 0, stream>>>(x, table, out, npoints, sc);
}

// Round 2
// 355.104 us; speedup vs baseline: 1.5282x; 1.5282x over previous
//
#include <hip/hip_runtime.h>
#include <cmath>

#define TBL_SIZE (1u << 19)
#define TBL_MASK (TBL_SIZE - 1u)
#define PRIME1 2654435761u
#define PRIME2 805459861u
#define NUM_LEVELS 16

struct ScaleArgs { float s[NUM_LEVELS]; };

// One block = one level (XCD-affine via blockIdx&7) x 256 consecutive points.
// Each XCD's 4 MiB L2 holds exactly its level's 4 MiB table slice.
__global__ __launch_bounds__(256) void HashEncoding_88837103551034_kernel(
    const float* __restrict__ x,
    const float* __restrict__ table,
    float* __restrict__ out,
    int npoints,
    int level_base,
    ScaleArgs sc)
{
    int b = blockIdx.x;
    int level = level_base + (b & 7);          // blockIdx%8 -> XCD affinity
    int n = (b >> 3) * 256 + (int)threadIdx.x; // point index
    if (n >= npoints) return;

    // x in [-1,1] -> [0,1]; same f32 ops as the reference
    float x0 = x[(size_t)n * 3 + 0] * 0.5f + 0.5f;
    float x1 = x[(size_t)n * 3 + 1] * 0.5f + 0.5f;
    float x2 = x[(size_t)n * 3 + 2] * 0.5f + 0.5f;

    float s = sc.s[level];
    float sx = x0 * s, sy = x1 * s, sz = x2 * s;
    float fx = floorf(sx), fy = floorf(sy), fz = floorf(sz);
    float ox = sx - fx, oy = sy - fy, oz = sz - fz;

    // uint32 products: low 19 bits identical to the int64 reference (coords >= 0)
    uint32_t hx0 = (uint32_t)(int)fx;                    // * 1
    uint32_t hx1 = (uint32_t)(int)ceilf(sx);
    uint32_t hy0 = (uint32_t)(int)fy        * PRIME1;
    uint32_t hy1 = (uint32_t)(int)ceilf(sy) * PRIME1;
    uint32_t hz0 = (uint32_t)(int)fz        * PRIME2;
    uint32_t hz1 = (uint32_t)(int)ceilf(sz) * PRIME2;

    const float2* tb = reinterpret_cast<const float2*>(table) + (size_t)level * TBL_SIZE;

    // Issue all 8 gathers first (MLP), then weight-accumulate.
    float2 f[8];
    #pragma unroll
    for (int c = 0; c < 8; ++c) {
        uint32_t h = ((c & 4) ? hx1 : hx0)
                   ^ ((c & 2) ? hy1 : hy0)
                   ^ ((c & 1) ? hz1 : hz0);
        f[c] = tb[h & TBL_MASK];
    }

    float e0 = 0.f, e1 = 0.f;
    #pragma unroll
    for (int c = 0; c < 8; ++c) {
        float w = ((c & 4) ? ox : 1.f - ox)
                * ((c & 2) ? oy : 1.f - oy)
                * ((c & 1) ? oz : 1.f - oz);
        e0 += f[c].x * w;
        e1 += f[c].y * w;
    }

    float2 res; res.x = e0; res.y = e1;
    *reinterpret_cast<float2*>(out + (size_t)n * (NUM_LEVELS * 2) + level * 2) = res;
}

extern "C" void kernel_launch(void* const* d_in, const int* in_sizes, int n_in,
                              void* d_out, int out_size, void* d_ws, size_t ws_size,
                              hipStream_t stream) {
    const float* x = (const float*)d_in[0];
    const float* table = (const float*)d_in[1];
    float* out = (float*)d_out;
    int npoints = in_sizes[0] / 3;

    // Per-level resolutions, replicating numpy's double-precision op sequence:
    // growth = exp((log(1024)-log(16))/15); s[l] = floor(16 * growth**l)
    ScaleArgs sc;
    double growth = std::exp((std::log(1024.0) - std::log(16.0)) / 15.0);
    for (int l = 0; l < NUM_LEVELS; ++l) {
        sc.s[l] = (float)std::floor(16.0 * std::pow(growth, (double)l));
    }

    int chunks = (npoints + 255) / 256;
    int grid = chunks * 8;
    // Pass A: levels 0..7 (one level per XCD), pass B: levels 8..15.
    HashEncoding_88837103551034_kernel<<<grid, 256, 0, stream>>>(x, table, out, npoints, 0, sc);
    HashEncoding_88837103551034_kernel<<<grid, 256, 0, stream>>>(x, table, out, npoints, 8, sc);
}

// Round 3
// 351.225 us; speedup vs baseline: 1.5451x; 1.0110x over previous
//
#include <hip/hip_runtime.h>
#include <cmath>

#define TBL_SIZE (1u << 19)
#define TBL_MASK (TBL_SIZE - 1u)
#define PRIME1 2654435761u
#define PRIME2 805459861u
#define NUM_LEVELS 16
#define HARD0 6          // levels >= 6 have ~4MB hot footprint ("hard"); 0..5 total 3.3MB ("easy")

struct ScaleArgs { float s[NUM_LEVELS]; };

typedef float v2f __attribute__((ext_vector_type(2)));

// Single dispatch, weight-free balanced XCD schedule:
//  - hard levels (6..15), 10*CH chunks, split contiguously: XCD i owns global hard
//    chunks [i*perXcdHard, (i+1)*perXcdHard) -> <=2 hard levels per XCD, processed
//    sequentially, each L2-resident (4MB) while active.
//  - easy levels (0..5, 3.3MB combined -- fits any XCD's L2) striped across all XCDs.
__global__ __launch_bounds__(256) void HashEncoding_88837103551034_kernel(
    const float* __restrict__ x,
    const float* __restrict__ table,
    float* __restrict__ out,
    int npoints, int CH, int perXcdHard, int hardTotal, int easyTotal,
    ScaleArgs sc)
{
    int b = blockIdx.x;
    int xcd = b & 7;
    int s = b >> 3;

    int level, chunk;
    if (s < perXcdHard) {
        int g = xcd * perXcdHard + s;          // global hard chunk id
        if (g >= hardTotal) return;
        int li = g / CH;
        level = HARD0 + li;
        chunk = g - li * CH;
    } else {
        int g = (s - perXcdHard) * 8 + xcd;    // global easy chunk id, striped
        if (g >= easyTotal) return;
        int li = g / CH;
        level = li;
        chunk = g - li * CH;
    }

    int n = chunk * 256 + (int)threadIdx.x;
    if (n >= npoints) return;

    // x in [-1,1] -> [0,1]; same f32 ops as the reference. NT: keep x out of L2.
    float x0 = __builtin_nontemporal_load(&x[(size_t)n * 3 + 0]) * 0.5f + 0.5f;
    float x1 = __builtin_nontemporal_load(&x[(size_t)n * 3 + 1]) * 0.5f + 0.5f;
    float x2 = __builtin_nontemporal_load(&x[(size_t)n * 3 + 2]) * 0.5f + 0.5f;

    float sl = sc.s[level];
    float sx = x0 * sl, sy = x1 * sl, sz = x2 * sl;
    float fx = floorf(sx), fy = floorf(sy), fz = floorf(sz);
    float ox = sx - fx, oy = sy - fy, oz = sz - fz;

    // uint32 products: low 19 bits identical to the int64 reference (coords >= 0)
    uint32_t hx0 = (uint32_t)(int)fx;                    // * 1
    uint32_t hx1 = (uint32_t)(int)ceilf(sx);
    uint32_t hy0 = (uint32_t)(int)fy        * PRIME1;
    uint32_t hy1 = (uint32_t)(int)ceilf(sy) * PRIME1;
    uint32_t hz0 = (uint32_t)(int)fz        * PRIME2;
    uint32_t hz1 = (uint32_t)(int)ceilf(sz) * PRIME2;

    const float2* tb = reinterpret_cast<const float2*>(table) + (size_t)level * TBL_SIZE;

    // Issue all 8 gathers first (MLP), then weight-accumulate.
    float2 f[8];
    #pragma unroll
    for (int c = 0; c < 8; ++c) {
        uint32_t h = ((c & 4) ? hx1 : hx0)
                   ^ ((c & 2) ? hy1 : hy0)
                   ^ ((c & 1) ? hz1 : hz0);
        f[c] = tb[h & TBL_MASK];
    }

    float e0 = 0.f, e1 = 0.f;
    #pragma unroll
    for (int c = 0; c < 8; ++c) {
        float w = ((c & 4) ? ox : 1.f - ox)
                * ((c & 2) ? oy : 1.f - oy)
                * ((c & 1) ? oz : 1.f - oz);
        e0 += f[c].x * w;
        e1 += f[c].y * w;
    }

    v2f res; res.x = e0; res.y = e1;
    // NT store: out lines are touched once per (point, level-pair); don't pollute L2.
    __builtin_nontemporal_store(res, (v2f*)(out + (size_t)n * (NUM_LEVELS * 2) + level * 2));
}

extern "C" void kernel_launch(void* const* d_in, const int* in_sizes, int n_in,
                              void* d_out, int out_size, void* d_ws, size_t ws_size,
                              hipStream_t stream) {
    const float* x = (const float*)d_in[0];
    const float* table = (const float*)d_in[1];
    float* out = (float*)d_out;
    int npoints = in_sizes[0] / 3;

    // Per-level resolutions, replicating numpy's double-precision op sequence:
    // growth = exp((log(1024)-log(16))/15); s[l] = floor(16 * growth**l)
    ScaleArgs sc;
    double growth = std::exp((std::log(1024.0) - std::log(16.0)) / 15.0);
    for (int l = 0; l < NUM_LEVELS; ++l) {
        sc.s[l] = (float)std::floor(16.0 * std::pow(growth, (double)l));
    }

    int CH = (npoints + 255) / 256;                 // chunks per level
    int nHard = NUM_LEVELS - HARD0;                 // 10
    int hardTotal = nHard * CH;
    int easyTotal = HARD0 * CH;
    int perXcdHard = (hardTotal + 7) / 8;
    int perXcdEasy = (easyTotal + 7) / 8;
    int grid = 8 * (perXcdHard + perXcdEasy);

    HashEncoding_88837103551034_kernel<<<grid, 256, 0, stream>>>(
        x, table, out, npoints, CH, perXcdHard, hardTotal, easyTotal, sc);
}

// Round 4
// 257.802 us; speedup vs baseline: 2.1051x; 1.3624x over previous
//
#include <hip/hip_runtime.h>
#include <cmath>

#define TBL_SIZE (1u << 19)
#define TBL_MASK (TBL_SIZE - 1u)
#define PRIME1 2654435761u
#define PRIME2 805459861u
#define NUM_LEVELS 16
#define HARD0 6          // levels >= 6 have ~4MB hot footprint
#define PPB 32           // points per 256-thread block (8 lanes per point)

struct ScaleArgs { float s[NUM_LEVELS]; };

typedef float v2f __attribute__((ext_vector_type(2)));

// Corner-per-lane: 8 consecutive lanes handle one (point, level); lane's corner
// = threadIdx&7. One 64-lane gather instruction covers 8 points x 8 corners
// (was 8 instructions) -> 8x fewer vmem instructions, same unique lines.
// Balanced XCD schedule retained (hard levels contiguous per XCD, easy striped).
__global__ __launch_bounds__(256) void HashEncoding_88837103551034_kernel(
    const float* __restrict__ x,
    const float* __restrict__ table,
    float* __restrict__ out,
    int npoints, int CH, int perXcdHard, int hardTotal, int easyTotal,
    ScaleArgs sc)
{
    int b = blockIdx.x;
    int xcd = b & 7;
    int s = b >> 3;

    int level, chunk;
    if (s < perXcdHard) {
        int g = xcd * perXcdHard + s;          // global hard chunk id
        if (g >= hardTotal) return;
        int li = g / CH;
        level = HARD0 + li;
        chunk = g - li * CH;
    } else {
        int g = (s - perXcdHard) * 8 + xcd;    // global easy chunk id, striped
        if (g >= easyTotal) return;
        int li = g / CH;
        level = li;
        chunk = g - li * CH;
    }

    int t = (int)threadIdx.x;
    int corner = t & 7;                        // this lane's cube corner
    int n = chunk * PPB + (t >> 3);            // point index
    if (n >= npoints) return;

    // x in [-1,1] -> [0,1]; same f32 ops as the reference. 8 lanes share these
    // loads -> TA merges same-line lane requests; L1-hit broadcast.
    float x0 = x[(size_t)n * 3 + 0] * 0.5f + 0.5f;
    float x1 = x[(size_t)n * 3 + 1] * 0.5f + 0.5f;
    float x2 = x[(size_t)n * 3 + 2] * 0.5f + 0.5f;

    float sl = sc.s[level];
    float sx = x0 * sl, sy = x1 * sl, sz = x2 * sl;
    float fx = floorf(sx), fy = floorf(sy), fz = floorf(sz);
    float ox = sx - fx, oy = sy - fy, oz = sz - fz;

    // This lane's corner coordinate per bit: bit set -> ceil, else floor.
    float cx = (corner & 4) ? ceilf(sx) : fx;
    float cy = (corner & 2) ? ceilf(sy) : fy;
    float cz = (corner & 1) ? ceilf(sz) : fz;

    // uint32 products: low 19 bits identical to the int64 reference (coords >= 0)
    uint32_t h = (uint32_t)(int)cx
               ^ ((uint32_t)(int)cy * PRIME1)
               ^ ((uint32_t)(int)cz * PRIME2);

    const float2* tb = reinterpret_cast<const float2*>(table) + (size_t)level * TBL_SIZE;
    float2 f = tb[h & TBL_MASK];

    float w = ((corner & 4) ? ox : 1.f - ox)
            * ((corner & 2) ? oy : 1.f - oy)
            * ((corner & 1) ? oz : 1.f - oz);

    float e0 = f.x * w;
    float e1 = f.y * w;

    // Sum the 8 corners across the 8-lane group (xor butterflies stay in-group).
    #pragma unroll
    for (int m = 1; m < 8; m <<= 1) {
        e0 += __shfl_xor(e0, m, 64);
        e1 += __shfl_xor(e1, m, 64);
    }

    if (corner == 0) {
        v2f res; res.x = e0; res.y = e1;
        __builtin_nontemporal_store(res, (v2f*)(out + (size_t)n * (NUM_LEVELS * 2) + level * 2));
    }
}

extern "C" void kernel_launch(void* const* d_in, const int* in_sizes, int n_in,
                              void* d_out, int out_size, void* d_ws, size_t ws_size,
                              hipStream_t stream) {
    const float* x = (const float*)d_in[0];
    const float* table = (const float*)d_in[1];
    float* out = (float*)d_out;
    int npoints = in_sizes[0] / 3;

    // Per-level resolutions, replicating numpy's double-precision op sequence:
    // growth = exp((log(1024)-log(16))/15); s[l] = floor(16 * growth**l)
    ScaleArgs sc;
    double growth = std::exp((std::log(1024.0) - std::log(16.0)) / 15.0);
    for (int l = 0; l < NUM_LEVELS; ++l) {
        sc.s[l] = (float)std::floor(16.0 * std::pow(growth, (double)l));
    }

    int CH = (npoints + PPB - 1) / PPB;             // chunks per level
    int nHard = NUM_LEVELS - HARD0;                 // 10
    int hardTotal = nHard * CH;
    int easyTotal = HARD0 * CH;
    int perXcdHard = (hardTotal + 7) / 8;
    int perXcdEasy = (easyTotal + 7) / 8;
    int grid = 8 * (perXcdHard + perXcdEasy);

    HashEncoding_88837103551034_kernel<<<grid, 256, 0, stream>>>(
        x, table, out, npoints, CH, perXcdHard, hardTotal, easyTotal, sc);
}

// Round 5
// 257.418 us; speedup vs baseline: 2.1082x; 1.0015x over previous
//
#include <hip/hip_runtime.h>
#include <cmath>

#define TBL_SIZE (1u << 19)
#define TBL_MASK (TBL_SIZE - 1u)
#define PRIME1 2654435761u
#define PRIME2 805459861u
#define NUM_LEVELS 16
#define HARD0 6          // levels >= 6 have ~4MB hot footprint
#define PPB 32           // points per 256-thread block (8 lanes per point)

struct ScaleArgs { float s[NUM_LEVELS]; };

typedef float v2f __attribute__((ext_vector_type(2)));

// v + dpp_mov<CTRL>(v) — pure-VALU cross-lane add (no LDS pipe, ~4cy latency).
template<int CTRL>
__device__ __forceinline__ float dpp_add(float v) {
    int i = __builtin_bit_cast(int, v);
    int j = __builtin_amdgcn_mov_dpp(i, CTRL, 0xF, 0xF, true);
    return v + __builtin_bit_cast(float, j);
}

// Corner-per-lane: 8 consecutive lanes handle one (point, level); lane's corner
// = threadIdx&7. One 64-lane gather instruction covers 8 points x 8 corners.
// 8-lane reduction via DPP: quad_perm xor1, quad_perm xor2, row_half_mirror
// (reverse within 8-lane half-row: lane 0 <- lane 7, lane 8 <- lane 15 — stays
// inside the point's lane group, no direction ambiguity).
__global__ __launch_bounds__(256) void HashEncoding_88837103551034_kernel(
    const float* __restrict__ x,
    const float* __restrict__ table,
    float* __restrict__ out,
    int npoints, int CH, int perXcdHard, int hardTotal, int easyTotal,
    ScaleArgs sc)
{
    int b = blockIdx.x;
    int xcd = b & 7;
    int s = b >> 3;

    int level, chunk;
    if (s < perXcdHard) {
        int g = xcd * perXcdHard + s;          // global hard chunk id (block-uniform math)
        if (g >= hardTotal) return;
        int li = g / CH;
        level = HARD0 + li;
        chunk = g - li * CH;
    } else {
        int g = (s - perXcdHard) * 8 + xcd;    // global easy chunk id, striped
        if (g >= easyTotal) return;
        int li = g / CH;
        level = li;
        chunk = g - li * CH;
    }

    int t = (int)threadIdx.x;
    int corner = t & 7;                        // this lane's cube corner
    int n = chunk * PPB + (t >> 3);            // point index
    if (n >= npoints) return;

    // x in [-1,1] -> [0,1]; same f32 ops as the reference.
    float x0 = x[(size_t)n * 3 + 0] * 0.5f + 0.5f;
    float x1 = x[(size_t)n * 3 + 1] * 0.5f + 0.5f;
    float x2 = x[(size_t)n * 3 + 2] * 0.5f + 0.5f;

    float sl = sc.s[level];
    float sx = x0 * sl, sy = x1 * sl, sz = x2 * sl;
    float fx = floorf(sx), fy = floorf(sy), fz = floorf(sz);
    float ox = sx - fx, oy = sy - fy, oz = sz - fz;

    int bx = (corner >> 2) & 1, by = (corner >> 1) & 1, bz = corner & 1;

    // ceil == floor+1 except when scaled coord is integral; there the reference's
    // ceil-corner weight is exactly 0.0, so the (different) index contributes 0
    // either way — the sum is unchanged.
    uint32_t h = (uint32_t)((int)fx + bx)
               ^ ((uint32_t)((int)fy + by) * PRIME1)
               ^ ((uint32_t)((int)fz + bz) * PRIME2);

    const float2* tb = reinterpret_cast<const float2*>(table) + (size_t)level * TBL_SIZE;
    float2 f = tb[h & TBL_MASK];

    float w = (bx ? ox : 1.f - ox)
            * (by ? oy : 1.f - oy)
            * (bz ? oz : 1.f - oz);

    float e0 = f.x * w;
    float e1 = f.y * w;

    // 8-lane sum, result valid in lanes with (t&7)==0.
    e0 = dpp_add<0xB1>(e0);  e1 = dpp_add<0xB1>(e1);   // quad_perm [1,0,3,2]  (xor 1)
    e0 = dpp_add<0x4E>(e0);  e1 = dpp_add<0x4E>(e1);   // quad_perm [2,3,0,1]  (xor 2)
    e0 = dpp_add<0x141>(e0); e1 = dpp_add<0x141>(e1);  // row_half_mirror      (0<-7)

    if (corner == 0) {
        v2f res; res.x = e0; res.y = e1;
        __builtin_nontemporal_store(res, (v2f*)(out + (size_t)n * (NUM_LEVELS * 2) + level * 2));
    }
}

extern "C" void kernel_launch(void* const* d_in, const int* in_sizes, int n_in,
                              void* d_out, int out_size, void* d_ws, size_t ws_size,
                              hipStream_t stream) {
    const float* x = (const float*)d_in[0];
    const float* table = (const float*)d_in[1];
    float* out = (float*)d_out;
    int npoints = in_sizes[0] / 3;

    // Per-level resolutions, replicating numpy's double-precision op sequence:
    // growth = exp((log(1024)-log(16))/15); s[l] = floor(16 * growth**l)
    ScaleArgs sc;
    double growth = std::exp((std::log(1024.0) - std::log(16.0)) / 15.0);
    for (int l = 0; l < NUM_LEVELS; ++l) {
        sc.s[l] = (float)std::floor(16.0 * std::pow(growth, (double)l));
    }

    int CH = (npoints + PPB - 1) / PPB;             // chunks per level
    int nHard = NUM_LEVELS - HARD0;                 // 10
    int hardTotal = nHard * CH;
    int easyTotal = HARD0 * CH;
    int perXcdHard = (hardTotal + 7) / 8;
    int perXcdEasy = (easyTotal + 7) / 8;
    int grid = 8 * (perXcdHard + perXcdEasy);

    HashEncoding_88837103551034_kernel<<<grid, 256, 0, stream>>>(
        x, table, out, npoints, CH, perXcdHard, hardTotal, easyTotal, sc);
}